// Round 10
// baseline (6108.005 us; speedup 1.0000x reference)
//
#include <hip/hip_runtime.h>
#include <stdint.h>
#include <math.h>

// NumPy SSE3-baseline numerics: separate mul+add everywhere, no contraction.
#pragma clang fp contract(off)

#define M_TOTAL 104448   // 51*2048
#define N_OUT   904      // 4 + 6*50*3
#define K_DIM   1024

#define BM 64
#define BN 64
#define BK 16            // = one numpy SIMD "group" (4 vectors x 4 lanes)

// ---------------- threefry2x32 (exact JAX/Random123) ----------------
__host__ __device__ inline uint32_t rotl32(uint32_t x, int r) {
    return (x << r) | (x >> (32 - r));
}

__host__ __device__ inline void threefry2x32(uint32_t k0, uint32_t k1,
                                             uint32_t x0, uint32_t x1,
                                             uint32_t& o0, uint32_t& o1) {
    uint32_t ks2 = k0 ^ k1 ^ 0x1BD11BDAu;
    x0 += k0; x1 += k1;
#define R4(a,b,c,d) \
    x0 += x1; x1 = rotl32(x1,(a)); x1 ^= x0; \
    x0 += x1; x1 = rotl32(x1,(b)); x1 ^= x0; \
    x0 += x1; x1 = rotl32(x1,(c)); x1 ^= x0; \
    x0 += x1; x1 = rotl32(x1,(d)); x1 ^= x0;
    R4(13,15,26,6)  x0 += k1;  x1 += ks2 + 1u;
    R4(17,29,16,24) x0 += ks2; x1 += k0  + 2u;
    R4(13,15,26,6)  x0 += k0;  x1 += k1  + 3u;
    R4(17,29,16,24) x0 += k1;  x1 += ks2 + 4u;
    R4(13,15,26,6)  x0 += ks2; x1 += k0  + 5u;
#undef R4
    o0 = x0; o1 = x1;
}

// jax_threefry_partitionable random_bits (confirmed by R6->R7 fingerprint move):
// element j: block = threefry2x32(key, (0, j)); 32-bit out = o0 ^ o1.
__device__ inline uint32_t random_bits_part(uint32_t k0, uint32_t k1, uint32_t idx) {
    uint32_t o0, o1;
    threefry2x32(k0, k1, 0u, idx, o0, o1);
    return o0 ^ o1;
}

__device__ inline float bits_to_unit(uint32_t bits) {
    return __uint_as_float((bits >> 9) | 0x3f800000u) - 1.0f;
}

// Correctly-rounded f32 transcendentals via double evaluation.
__device__ inline float logf_cr(float x) { return (float)log((double)x); }
__device__ inline float expf_cr(float x) { return (float)exp((double)x); }

__device__ inline float gumbel_at(uint32_t k0, uint32_t k1, uint32_t idx) {
    float f = bits_to_unit(random_bits_part(k0, k1, idx));
    float u = fmaxf(f, 1.17549435e-38f);   // uniform(tiny, 1)
    float t = logf_cr(u);
    return -logf_cr(-t);
}

// ErfInv (f32), Giles polynomial — continuous path, bf16-invisible tolerance
__device__ inline float erfinv_xla(float x) {
    float w = -log1pf(-x * x);
    float p;
    if (w < 5.0f) {
        w = w - 2.5f;
        p = 2.81022636e-08f;
        p = 3.43273939e-07f  + p * w;
        p = -3.5233877e-06f  + p * w;
        p = -4.39150654e-06f + p * w;
        p = 0.00021858087f   + p * w;
        p = -0.00125372503f  + p * w;
        p = -0.00417768164f  + p * w;
        p = 0.246640727f     + p * w;
        p = 1.50140941f      + p * w;
    } else {
        w = sqrtf(w) - 3.0f;
        p = -0.000200214257f;
        p = 0.000100950558f  + p * w;
        p = 0.00134934322f   + p * w;
        p = -0.00367342844f  + p * w;
        p = 0.00573950773f   + p * w;
        p = -0.0076224613f   + p * w;
        p = 0.00943887047f   + p * w;
        p = 1.00167406f      + p * w;
        p = 2.83297682f      + p * w;
    }
    return p * x;
}

// ---------------- Kernel A: GEMM, numpy einsum SSE3 SOP replica ----------------
// Per output element (numpy sum_of_products_contig_contig_outstride0_two,
// SSE3 baseline: 4 lanes, no FMA):
//   lane j accumulates k ≡ j (mod 4); groups of 16 ascending; within group
//   the 4 quads chain in REVERSE: acc_j = p_{j} + (p_{4+j} + (p_{8+j} + (p_{12+j} + acc_j)))
//   (each p single-rounded mul, each add rounded);
//   final fold (hadd tree): res = (s0+s1) + (s2+s3); then res + bias.
// Order-preserving visit: k = 12..15, 8..11, 4..7, 0..3 per group, acc_j = p + acc_j.
__global__ __launch_bounds__(256) void gemm_np_sse(
    const float* __restrict__ X,      // (rows, 1024) — already offset to chunk
    const float* __restrict__ W,      // (904, 1024)
    const float* __restrict__ bias,   // (904,)
    float* __restrict__ ret,          // (rows, 904)
    int rows)
{
    __shared__ float As[BK][BM];   // [k][m]
    __shared__ float Bs[BK][BN];   // [k][n]

    const int t  = threadIdx.x;
    const int tx = t & 15;     // n dir (4 cols each)
    const int ty = t >> 4;     // m dir (4 rows each)
    const int m0 = blockIdx.y * BM;
    const int n0 = blockIdx.x * BN;

    const int lrow = t >> 2;          // 0..63
    const int lc4  = (t & 3) * 4;     // 0,4,8,12

    // acc[i][j][lane], lane = k mod 4 — all indices compile-time (rule #20)
    float acc[4][4][4];
#pragma unroll
    for (int i = 0; i < 4; i++)
#pragma unroll
        for (int j = 0; j < 4; j++)
#pragma unroll
            for (int l = 0; l < 4; l++) acc[i][j][l] = 0.0f;

    for (int k0 = 0; k0 < K_DIM; k0 += BK) {
        float4 av = *(const float4*)(X + (size_t)(m0 + lrow) * K_DIM + k0 + lc4);
        float4 bv;
        int go = n0 + lrow;
        if (go < N_OUT) bv = *(const float4*)(W + (size_t)go * K_DIM + k0 + lc4);
        else            bv = make_float4(0.f, 0.f, 0.f, 0.f);

        __syncthreads();
        As[lc4 + 0][lrow] = av.x; As[lc4 + 1][lrow] = av.y;
        As[lc4 + 2][lrow] = av.z; As[lc4 + 3][lrow] = av.w;
        Bs[lc4 + 0][lrow] = bv.x; Bs[lc4 + 1][lrow] = bv.y;
        Bs[lc4 + 2][lrow] = bv.z; Bs[lc4 + 3][lrow] = bv.w;
        __syncthreads();

        // reverse-quad order: q = 3,2,1,0; lane kk = k mod 4
#pragma unroll
        for (int q = 3; q >= 0; q--) {
#pragma unroll
            for (int kk = 0; kk < 4; kk++) {
                const int k = q * 4 + kk;
                float4 af = *(const float4*)&As[k][ty * 4];
                float4 bf = *(const float4*)&Bs[k][tx * 4];
                // contract(off): v_mul + v_add, two roundings — numpy muladd emulation
                acc[0][0][kk] = af.x * bf.x + acc[0][0][kk];
                acc[0][1][kk] = af.x * bf.y + acc[0][1][kk];
                acc[0][2][kk] = af.x * bf.z + acc[0][2][kk];
                acc[0][3][kk] = af.x * bf.w + acc[0][3][kk];
                acc[1][0][kk] = af.y * bf.x + acc[1][0][kk];
                acc[1][1][kk] = af.y * bf.y + acc[1][1][kk];
                acc[1][2][kk] = af.y * bf.z + acc[1][2][kk];
                acc[1][3][kk] = af.y * bf.w + acc[1][3][kk];
                acc[2][0][kk] = af.z * bf.x + acc[2][0][kk];
                acc[2][1][kk] = af.z * bf.y + acc[2][1][kk];
                acc[2][2][kk] = af.z * bf.z + acc[2][2][kk];
                acc[2][3][kk] = af.z * bf.w + acc[2][3][kk];
                acc[3][0][kk] = af.w * bf.x + acc[3][0][kk];
                acc[3][1][kk] = af.w * bf.y + acc[3][1][kk];
                acc[3][2][kk] = af.w * bf.z + acc[3][2][kk];
                acc[3][3][kk] = af.w * bf.w + acc[3][3][kk];
            }
        }
    }

#pragma unroll
    for (int i = 0; i < 4; i++) {
        int m = m0 + ty * 4 + i;
        if (m >= rows) continue;
#pragma unroll
        for (int j = 0; j < 4; j++) {
            int o = n0 + tx * 4 + j;
            if (o >= N_OUT) continue;
            // hadd tree fold
            float res = (acc[i][j][0] + acc[i][j][1]) + (acc[i][j][2] + acc[i][j][3]);
            ret[(size_t)m * N_OUT + o] = res + bias[o];
        }
    }
}

// ---------------- Kernel B: sampling (one wave per (s,b) row) ----------------
__global__ __launch_bounds__(256) void sample_kernel(
    const float* __restrict__ ret,   // (rows, 904) chunk
    float* __restrict__ out,         // (M_TOTAL, 10)
    int m0_global, int rows,
    uint32_t kc0, uint32_t kc1,
    uint32_t km0, uint32_t km1,
    uint32_t kg0, uint32_t kg1)
{
    const int lane = threadIdx.x & 63;
    const int wid  = threadIdx.x >> 6;
    const int rloc = blockIdx.x * 4 + wid;
    if (rloc >= rows) return;
    const int m = m0_global + rloc;

    const float* r = ret + (size_t)rloc * N_OUT;
    float* o = out + (size_t)m * 10;

    const float LO = __uint_as_float(0xBF7FFFFFu);      // nextafter(-1, 0)
    const float SQRT2 = __uint_as_float(0x3FB504F3u);   // f32(sqrt(2))

    // ---- command: argmax(ret[:4]/1e-4 + gumbel) ----
    {
        float v; int idx = lane;
        if (lane < 4) {
            float g = gumbel_at(kc0, kc1, (uint32_t)(m * 4 + lane));
            v = r[lane] / 0.0001f + g;
        } else {
            v = -INFINITY;
        }
#pragma unroll
        for (int off = 1; off < 64; off <<= 1) {
            float v2 = __shfl_xor(v, off);
            int   i2 = __shfl_xor(idx, off);
            if (v2 > v || (v2 == v && i2 < idx)) { v = v2; idx = i2; }
        }
        if (lane < 4) o[lane] = (lane == idx) ? 1.0f : 0.0f;
    }

    // ---- 6 mixture groups ----
    for (int a = 0; a < 6; a++) {
        const float* base = r + 4 + a * 150;
        float l = (lane < 50) ? base[lane] : -INFINITY;

        float mx = l;
#pragma unroll
        for (int off = 1; off < 64; off <<= 1) mx = fmaxf(mx, __shfl_xor(mx, off));

        float e = (lane < 50) ? expf_cr(l - mx) : 0.0f;

        // numpy pairwise sum, n=50: r_j = e_j + e_{8+j} + ... + e_{40+j} (sequential),
        // s = ((r0+r1)+(r2+r3)) + ((r4+r5)+(r6+r7)); s += e48; s += e49
        float rj = (lane < 8) ? e : 0.0f;
#pragma unroll
        for (int tstep = 1; tstep <= 5; tstep++) {
            float ev = __shfl(e, (lane & 7) + 8 * tstep);
            if (lane < 8) rj = rj + ev;
        }
        float r0 = __shfl(rj, 0), r1 = __shfl(rj, 1), r2 = __shfl(rj, 2), r3 = __shfl(rj, 3);
        float r4 = __shfl(rj, 4), r5 = __shfl(rj, 5), r6 = __shfl(rj, 6), r7 = __shfl(rj, 7);
        float s = ((r0 + r1) + (r2 + r3)) + ((r4 + r5) + (r6 + r7));
        s = s + __shfl(e, 48);
        s = s + __shfl(e, 49);

        float lse = logf_cr(s) + mx;

        float vv; int ii = lane;
        if (lane < 50) {
            float g = gumbel_at(km0, km1, (uint32_t)((m * 6 + a) * 50 + lane));
            vv = (l - lse) / 0.0001f + g;
        } else {
            vv = -INFINITY;
        }
#pragma unroll
        for (int off = 1; off < 64; off <<= 1) {
            float v2 = __shfl_xor(vv, off);
            int   i2 = __shfl_xor(ii, off);
            if (v2 > vv || (v2 == vv && i2 < ii)) { vv = v2; ii = i2; }
        }

        if (lane == 0) {
            float mean = base[50 + ii];
            float lstd = base[100 + ii];
            uint32_t eidx = (uint32_t)(m * 6 + a);
            float f = bits_to_unit(random_bits_part(kg0, kg1, eidx));
            float val = f * 2.0f + LO;        // f*(hi-lo)+lo, (hi-lo) rounds to 2.0f
            val = fmaxf(LO, val);
            float nrm = SQRT2 * erfinv_xla(val);
            float noise = nrm * 0.01f;        // * f32(sqrt(1e-4))
            o[4 + a] = mean + expf_cr(lstd) * noise;
        }
    }
}

// ---------------- host ----------------
extern "C" void kernel_launch(void* const* d_in, const int* in_sizes, int n_in,
                              void* d_out, int out_size, void* d_ws, size_t ws_size,
                              hipStream_t stream) {
    const float* X    = (const float*)d_in[0];  // (51,2048,1024)
    const float* W    = (const float*)d_in[1];  // (904,1024)
    const float* bias = (const float*)d_in[2];  // (904,)
    float* out = (float*)d_out;                 // (51,2048,10)
    float* ws  = (float*)d_ws;

    // key(42) = (0,42); partitionable (fold-like) split into 3:
    // key_i = full cipher block threefry2x32(key, (0, i))
    uint32_t kc0, kc1, km0, km1, kg0, kg1;
    threefry2x32(0u, 42u, 0u, 0u, kc0, kc1);   // k_cmd
    threefry2x32(0u, 42u, 0u, 1u, km0, km1);   // k_mix
    threefry2x32(0u, 42u, 0u, 2u, kg0, kg1);   // k_gauss

    const size_t rowBytes = (size_t)N_OUT * sizeof(float);
    size_t rowsCap = ws_size / rowBytes;
    int chunk = (rowsCap >= (size_t)M_TOTAL) ? M_TOTAL : (int)rowsCap;
    chunk -= chunk % BM;
    if (chunk <= 0) chunk = BM;

    const int gx = (N_OUT + BN - 1) / BN;

    for (int m0 = 0; m0 < M_TOTAL; m0 += chunk) {
        int rows = M_TOTAL - m0;
        if (rows > chunk) rows = chunk;
        dim3 ggrid(gx, rows / BM);
        gemm_np_sse<<<ggrid, 256, 0, stream>>>(X + (size_t)m0 * K_DIM, W, bias, ws, rows);
        sample_kernel<<<dim3(rows / 4), 256, 0, stream>>>(ws, out, m0, rows,
                                                          kc0, kc1, km0, km1, kg0, kg1);
    }
}